// Round 1
// baseline (998.143 us; speedup 1.0000x reference)
//
#include <hip/hip_runtime.h>
#include <cmath>

#define EPSBN 1e-5f

namespace {
constexpr int CN   = 2;    // N
constexpr int C_IN = 512;  // C
constexpr int CC   = 64;   // compressed channels
constexpr int CD   = 8;    // D
constexpr int CH   = 16;   // H
constexpr int CW   = 16;   // W
constexpr int HW   = CH * CW;   // 256
constexpr int DHW  = CD * HW;   // 2048
constexpr int QSZ  = CN * CC * DHW;  // 262144 floats per q/k/v/Patt/Datt buffer
}

// ---------------------------------------------------------------------------
// Kernel 1: q/k/v = relu(BN(1x1x1 conv(x) + bias))
// grid = (N*D) * 12 blocks; each block: one (n,d) slice (256 positions) x 16
// output channels. LDS-stages x in 32-channel chunks; weights are
// block-uniform (scalar loads).
// ---------------------------------------------------------------------------
__global__ __launch_bounds__(256) void qkv_kernel(
    const float* __restrict__ x,
    const float* __restrict__ Wq, const float* __restrict__ bq,
    const float* __restrict__ gq, const float* __restrict__ btq,
    const float* __restrict__ mq, const float* __restrict__ vq,
    const float* __restrict__ Wk, const float* __restrict__ bk,
    const float* __restrict__ gk, const float* __restrict__ btk,
    const float* __restrict__ mk, const float* __restrict__ vk,
    const float* __restrict__ Wv, const float* __restrict__ bv,
    const float* __restrict__ gv, const float* __restrict__ btv,
    const float* __restrict__ mv, const float* __restrict__ vv,
    float* __restrict__ outq, float* __restrict__ outk, float* __restrict__ outv)
{
    int bid = blockIdx.x;          // 0..191
    int nd  = bid / 12;
    int ocg = bid % 12;
    int n = nd >> 3, d = nd & 7;
    int branch = ocg >> 2;         // 0=q 1=k 2=v
    int oc0 = (ocg & 3) * 16;

    const float* Wsel  = branch == 0 ? Wq  : branch == 1 ? Wk  : Wv;
    const float* bsel  = branch == 0 ? bq  : branch == 1 ? bk  : bv;
    const float* gsel  = branch == 0 ? gq  : branch == 1 ? gk  : gv;
    const float* btsel = branch == 0 ? btq : branch == 1 ? btk : btv;
    const float* msel  = branch == 0 ? mq  : branch == 1 ? mk  : mv;
    const float* vsel  = branch == 0 ? vq  : branch == 1 ? vk  : vv;
    float*       osel  = branch == 0 ? outq : branch == 1 ? outk : outv;

    __shared__ float xs[32 * 256];
    int t = threadIdx.x;
    const float* xb = x + (size_t)n * C_IN * DHW + d * HW + t;

    float acc[16];
#pragma unroll
    for (int i = 0; i < 16; ++i) acc[i] = 0.f;

    for (int c0 = 0; c0 < C_IN; c0 += 32) {
        __syncthreads();
#pragma unroll
        for (int i = 0; i < 32; ++i)
            xs[i * 256 + t] = xb[(size_t)(c0 + i) * DHW];
        __syncthreads();
#pragma unroll 8
        for (int i = 0; i < 32; ++i) {
            float xv = xs[i * 256 + t];
            const float* wr = Wsel + (c0 + i);
#pragma unroll
            for (int oc = 0; oc < 16; ++oc)
                acc[oc] = fmaf(xv, wr[(oc0 + oc) * C_IN], acc[oc]);
        }
    }

#pragma unroll
    for (int oc = 0; oc < 16; ++oc) {
        int c = oc0 + oc;
        float s   = gsel[c] * rsqrtf(vsel[c] + EPSBN);
        float val = (acc[oc] + bsel[c] - msel[c]) * s + btsel[c];
        osel[((size_t)(n * CC + c) * CD + d) * HW + t] = fmaxf(val, 0.f);
    }
}

// ---------------------------------------------------------------------------
// Kernel 2: spatial attention Patt. One block per (n,c,d) slice; L=256.
// out[j] = sum_i (v_i/den_i) * exp(q_i*(k_j - kmax)),
// den_i = sum_j exp(q_i*(k_j - kmax)).  Shift q_i*kmax == jax softmax max
// (q,k >= 0 after ReLU).
// ---------------------------------------------------------------------------
__global__ __launch_bounds__(256) void patt_kernel(
    const float* __restrict__ q, const float* __restrict__ k,
    const float* __restrict__ v, float* __restrict__ out)
{
    int b = blockIdx.x;            // 0..1023 = (n,c,d)
    size_t base = (size_t)b * HW;
    __shared__ float sk[256], sq[256], sw[256];
    int t = threadIdx.x;
    float kt = k[base + t];
    float qt = q[base + t];
    float vt = v[base + t];
    sk[t] = kt;
    sq[t] = qt;
    __syncthreads();

    // block-uniform max over k (broadcast LDS reads)
    float kmax = 0.f;  // k >= 0
    for (int j = 0; j < 256; ++j) kmax = fmaxf(kmax, sk[j]);

    float den = 0.f;
    float qkm = qt * kmax;
    for (int j = 0; j < 256; ++j)
        den += __expf(qt * sk[j] - qkm);
    sw[t] = vt / den;
    __syncthreads();

    float kjm = kt - kmax;
    float o = 0.f;
    for (int i = 0; i < 256; ++i)
        o += sw[i] * __expf(sq[i] * kjm);
    out[base + t] = o;
}

// ---------------------------------------------------------------------------
// Kernel 3: temporal attention Datt. One thread per (n,c,h,w); D=8 in regs.
// ---------------------------------------------------------------------------
__global__ __launch_bounds__(256) void datt_kernel(
    const float* __restrict__ q, const float* __restrict__ k,
    const float* __restrict__ v, float* __restrict__ out)
{
    int t = blockIdx.x * 256 + threadIdx.x;   // 0..32767 = (n,c)*256 + hw
    int nc = t >> 8, hw = t & 255;
    size_t base = (size_t)nc * DHW + hw;

    float qv[8], kv[8], vv_[8];
#pragma unroll
    for (int d = 0; d < 8; ++d) {
        qv[d]  = q[base + d * HW];
        kv[d]  = k[base + d * HW];
        vv_[d] = v[base + d * HW];
    }
    float kmax = 0.f;
#pragma unroll
    for (int d = 0; d < 8; ++d) kmax = fmaxf(kmax, kv[d]);

    float wgt[8];
#pragma unroll
    for (int i = 0; i < 8; ++i) {
        float den = 0.f, qkm = qv[i] * kmax;
#pragma unroll
        for (int j = 0; j < 8; ++j)
            den += __expf(qv[i] * kv[j] - qkm);
        wgt[i] = vv_[i] / den;
    }
#pragma unroll
    for (int j = 0; j < 8; ++j) {
        float o = 0.f, kjm = kv[j] - kmax;
#pragma unroll
        for (int i = 0; i < 8; ++i)
            o += wgt[i] * __expf(qv[i] * kjm);
        out[base + j * HW] = o;
    }
}

// ---------------------------------------------------------------------------
// Kernel 4: fused dual 3x3x3 conv (64->512) + BN + ReLU + gama*(a+b)+x.
// grid = (N*D) * 128 blocks; block = 256 threads = one (h,w) slice; each block
// computes 4 output channels. Inputs staged in LDS in 8-channel chunks.
// ---------------------------------------------------------------------------
__global__ __launch_bounds__(256) void conv_out_kernel(
    const float* __restrict__ P, const float* __restrict__ Dt,
    const float* __restrict__ Ws, const float* __restrict__ bs,
    const float* __restrict__ gs, const float* __restrict__ bts,
    const float* __restrict__ ms, const float* __restrict__ vs,
    const float* __restrict__ Wd, const float* __restrict__ bd_,
    const float* __restrict__ gd, const float* __restrict__ btd,
    const float* __restrict__ md, const float* __restrict__ vd,
    const float* __restrict__ x, const float* __restrict__ gama,
    float* __restrict__ out)
{
    int bid = blockIdx.x;            // 0..2047
    int cog = bid & 127;
    int nd  = bid >> 7;
    int n = nd >> 3, d = nd & 7;
    int co0 = cog * 4;
    int t = threadIdx.x;
    int h = t >> 4, w = t & 15;

    __shared__ float pl[8 * 3 * 256];
    __shared__ float dl[8 * 3 * 256];

    float accP[4] = {0.f, 0.f, 0.f, 0.f};
    float accD[4] = {0.f, 0.f, 0.f, 0.f};

    for (int ci0 = 0; ci0 < CC; ci0 += 8) {
        __syncthreads();
#pragma unroll
        for (int ci = 0; ci < 8; ++ci) {
#pragma unroll
            for (int kd = 0; kd < 3; ++kd) {
                int dd = d + kd - 1;
                float pv = 0.f, dv = 0.f;
                if (dd >= 0 && dd < CD) {
                    size_t src = ((size_t)(n * CC + ci0 + ci) * CD + dd) * HW + t;
                    pv = P[src];
                    dv = Dt[src];
                }
                pl[(ci * 3 + kd) * 256 + t] = pv;
                dl[(ci * 3 + kd) * 256 + t] = dv;
            }
        }
        __syncthreads();

        for (int ci = 0; ci < 8; ++ci) {
            const float* wsb = Ws + ((size_t)co0 * CC + (ci0 + ci)) * 27;
            const float* wdb = Wd + ((size_t)co0 * CC + (ci0 + ci)) * 27;
#pragma unroll
            for (int kd = 0; kd < 3; ++kd) {
                const float* plp = &pl[(ci * 3 + kd) * 256];
                const float* dlp = &dl[(ci * 3 + kd) * 256];
#pragma unroll
                for (int kh = 0; kh < 3; ++kh) {
                    int hh = h + kh - 1;
                    bool hok = (unsigned)hh < 16u;
#pragma unroll
                    for (int kw = 0; kw < 3; ++kw) {
                        int ww = w + kw - 1;
                        bool ok = hok && ((unsigned)ww < 16u);
                        float vp = 0.f, vdv = 0.f;
                        if (ok) {
                            int off = hh * 16 + ww;
                            vp  = plp[off];
                            vdv = dlp[off];
                        }
                        int wi = (kd * 3 + kh) * 3 + kw;
#pragma unroll
                        for (int tt = 0; tt < 4; ++tt) {
                            accP[tt] = fmaf(vp,  wsb[tt * (CC * 27) + wi], accP[tt]);
                            accD[tt] = fmaf(vdv, wdb[tt * (CC * 27) + wi], accD[tt]);
                        }
                    }
                }
            }
        }
    }

    float g = gama[0];
#pragma unroll
    for (int tt = 0; tt < 4; ++tt) {
        int co = co0 + tt;
        float sP = gs[co] * rsqrtf(vs[co] + EPSBN);
        float rp = fmaxf((accP[tt] + bs[co] - ms[co]) * sP + bts[co], 0.f);
        float sD = gd[co] * rsqrtf(vd[co] + EPSBN);
        float rd = fmaxf((accD[tt] + bd_[co] - md[co]) * sD + btd[co], 0.f);
        size_t oi = ((size_t)(n * C_IN + co) * CD + d) * HW + t;
        out[oi] = g * (rp + rd) + x[oi];
    }
}

// ---------------------------------------------------------------------------
extern "C" void kernel_launch(void* const* d_in, const int* in_sizes, int n_in,
                              void* d_out, int out_size, void* d_ws, size_t ws_size,
                              hipStream_t stream)
{
    const float* x    = (const float*)d_in[0];
    const float* gama = (const float*)d_in[1];
    const float* Wq  = (const float*)d_in[2];
    const float* bq  = (const float*)d_in[3];
    const float* gq  = (const float*)d_in[4];
    const float* btq = (const float*)d_in[5];
    const float* mq  = (const float*)d_in[6];
    const float* vq  = (const float*)d_in[7];
    const float* Wk  = (const float*)d_in[8];
    const float* bk  = (const float*)d_in[9];
    const float* gk  = (const float*)d_in[10];
    const float* btk = (const float*)d_in[11];
    const float* mk  = (const float*)d_in[12];
    const float* vk  = (const float*)d_in[13];
    const float* Wv  = (const float*)d_in[14];
    const float* bv  = (const float*)d_in[15];
    const float* gv  = (const float*)d_in[16];
    const float* btv = (const float*)d_in[17];
    const float* mv  = (const float*)d_in[18];
    const float* vv  = (const float*)d_in[19];
    const float* Ws  = (const float*)d_in[20];
    const float* bs  = (const float*)d_in[21];
    const float* gs  = (const float*)d_in[22];
    const float* bts = (const float*)d_in[23];
    const float* ms  = (const float*)d_in[24];
    const float* vs  = (const float*)d_in[25];
    const float* Wd  = (const float*)d_in[26];
    const float* bd  = (const float*)d_in[27];
    const float* gd  = (const float*)d_in[28];
    const float* btd = (const float*)d_in[29];
    const float* md  = (const float*)d_in[30];
    const float* vd  = (const float*)d_in[31];

    float* q  = (float*)d_ws;
    float* k  = q + QSZ;
    float* v  = k + QSZ;
    float* P  = v + QSZ;
    float* Dt = P + QSZ;

    qkv_kernel<<<192, 256, 0, stream>>>(
        x,
        Wq, bq, gq, btq, mq, vq,
        Wk, bk, gk, btk, mk, vk,
        Wv, bv, gv, btv, mv, vv,
        q, k, v);

    patt_kernel<<<1024, 256, 0, stream>>>(q, k, v, P);
    datt_kernel<<<128, 256, 0, stream>>>(q, k, v, Dt);

    conv_out_kernel<<<2048, 256, 0, stream>>>(
        P, Dt,
        Ws, bs, gs, bts, ms, vs,
        Wd, bd, gd, btd, md, vd,
        x, gama, (float*)d_out);
}

// Round 2
// 185.070 us; speedup vs baseline: 5.3933x; 5.3933x over previous
//
#include <hip/hip_runtime.h>
#include <cmath>

#define EPSBN 1e-5f

namespace {
constexpr int C_IN = 512;
constexpr int CC   = 64;
constexpr int CD   = 8;
constexpr int CH   = 16;
constexpr int CW   = 16;
constexpr int HW   = CH * CW;        // 256
constexpr int DHW  = CD * HW;        // 2048
constexpr int QSZ  = 2 * CC * DHW;   // 262144 floats per q/k/v buffer

// padded input layout for conv: [n 2][dp 10][g 8][row 18][col 18][cil 8] bf16
constexpr int PG    = 18 * 18;           // 324 positions per padded plane
constexpr int GPLN  = PG * 8;            // 2592 elems per (dp,g) plane
constexpr int PADSZ = 2 * 10 * 8 * GPLN; // 414720 elems per branch
// Wt layout: [branch][tap 27][co 512][ci 64] bf16
constexpr int WTSZ  = 27 * 512 * 64;     // per branch elems

typedef __attribute__((ext_vector_type(8))) short bf16x8;
typedef __attribute__((ext_vector_type(4))) float f32x4;

__device__ inline unsigned short f2bf(float f) {
    unsigned u = __float_as_uint(f);
    return (unsigned short)((u + 0x7fffu + ((u >> 16) & 1u)) >> 16);
}
}

// ---------------------------------------------------------------------------
// zero the padded P/D buffers (borders must be 0 every call)
// ---------------------------------------------------------------------------
__global__ __launch_bounds__(256) void zero_pads_kernel(uint4* __restrict__ p)
{
    p[blockIdx.x * 256 + threadIdx.x] = make_uint4(0, 0, 0, 0);
}

// ---------------------------------------------------------------------------
// weight transpose: W[co][ci][27] fp32 -> Wt[branch][tap][co][ci] bf16
// ---------------------------------------------------------------------------
__global__ __launch_bounds__(256) void wtrans_kernel(
    const float* __restrict__ Ws, const float* __restrict__ Wd,
    unsigned short* __restrict__ Wt)
{
    int b  = blockIdx.x >> 9;
    int co = blockIdx.x & 511;
    const float* W = b ? Wd : Ws;
    unsigned short* o = Wt + (size_t)b * WTSZ;
    for (int k = threadIdx.x; k < 27 * 64; k += 256) {
        int tap = k >> 6, ci = k & 63;
        float w = W[((size_t)co * 64 + ci) * 27 + tap];
        o[((size_t)tap * 512 + co) * 64 + ci] = f2bf(w);
    }
}

// ---------------------------------------------------------------------------
// q/k/v = relu(BN(1x1x1 conv(x))) (fp32, unchanged from round 0)
// ---------------------------------------------------------------------------
__global__ __launch_bounds__(256) void qkv_kernel(
    const float* __restrict__ x,
    const float* __restrict__ Wq, const float* __restrict__ bq,
    const float* __restrict__ gq, const float* __restrict__ btq,
    const float* __restrict__ mq, const float* __restrict__ vq,
    const float* __restrict__ Wk, const float* __restrict__ bk,
    const float* __restrict__ gk, const float* __restrict__ btk,
    const float* __restrict__ mk, const float* __restrict__ vk,
    const float* __restrict__ Wv, const float* __restrict__ bv,
    const float* __restrict__ gv, const float* __restrict__ btv,
    const float* __restrict__ mv, const float* __restrict__ vv,
    float* __restrict__ outq, float* __restrict__ outk, float* __restrict__ outv)
{
    int bid = blockIdx.x;
    int nd  = bid / 12;
    int ocg = bid % 12;
    int n = nd >> 3, d = nd & 7;
    int branch = ocg >> 2;
    int oc0 = (ocg & 3) * 16;

    const float* Wsel  = branch == 0 ? Wq  : branch == 1 ? Wk  : Wv;
    const float* bsel  = branch == 0 ? bq  : branch == 1 ? bk  : bv;
    const float* gsel  = branch == 0 ? gq  : branch == 1 ? gk  : gv;
    const float* btsel = branch == 0 ? btq : branch == 1 ? btk : btv;
    const float* msel  = branch == 0 ? mq  : branch == 1 ? mk  : mv;
    const float* vsel  = branch == 0 ? vq  : branch == 1 ? vk  : vv;
    float*       osel  = branch == 0 ? outq : branch == 1 ? outk : outv;

    __shared__ float xs[32 * 256];
    int t = threadIdx.x;
    const float* xb = x + (size_t)n * C_IN * DHW + d * HW + t;

    float acc[16];
#pragma unroll
    for (int i = 0; i < 16; ++i) acc[i] = 0.f;

    for (int c0 = 0; c0 < C_IN; c0 += 32) {
        __syncthreads();
#pragma unroll
        for (int i = 0; i < 32; ++i)
            xs[i * 256 + t] = xb[(size_t)(c0 + i) * DHW];
        __syncthreads();
#pragma unroll 8
        for (int i = 0; i < 32; ++i) {
            float xv = xs[i * 256 + t];
            const float* wr = Wsel + (c0 + i);
#pragma unroll
            for (int oc = 0; oc < 16; ++oc)
                acc[oc] = fmaf(xv, wr[(oc0 + oc) * C_IN], acc[oc]);
        }
    }

#pragma unroll
    for (int oc = 0; oc < 16; ++oc) {
        int c = oc0 + oc;
        float s   = gsel[c] * rsqrtf(vsel[c] + EPSBN);
        float val = (acc[oc] + bsel[c] - msel[c]) * s + btsel[c];
        osel[((size_t)(n * CC + c) * CD + d) * HW + t] = fmaxf(val, 0.f);
    }
}

// ---------------------------------------------------------------------------
// spatial attention -> writes bf16 into padded layout
// ---------------------------------------------------------------------------
__global__ __launch_bounds__(256) void patt_kernel(
    const float* __restrict__ q, const float* __restrict__ k,
    const float* __restrict__ v, unsigned short* __restrict__ Pp)
{
    int b = blockIdx.x;            // (n,c,d)
    int n = b >> 9, c = (b >> 3) & 63, d = b & 7;
    size_t base = (size_t)b * HW;
    __shared__ float sk[256], sq[256], sw[256];
    int t = threadIdx.x;
    float kt = k[base + t];
    float qt = q[base + t];
    float vt = v[base + t];
    sk[t] = kt;
    sq[t] = qt;
    __syncthreads();

    float kmax = 0.f;
    for (int j = 0; j < 256; ++j) kmax = fmaxf(kmax, sk[j]);

    float den = 0.f;
    float qkm = qt * kmax;
    for (int j = 0; j < 256; ++j)
        den += __expf(qt * sk[j] - qkm);
    sw[t] = vt / den;
    __syncthreads();

    float kjm = kt - kmax;
    float o = 0.f;
    for (int i = 0; i < 256; ++i)
        o += sw[i] * __expf(sq[i] * kjm);

    int h = t >> 4, w = t & 15;
    size_t dst = ((((size_t)(n * 10 + d + 1) * 8 + (c >> 3)) * PG)
                  + (h + 1) * 18 + (w + 1)) * 8 + (c & 7);
    Pp[dst] = f2bf(o);
}

// ---------------------------------------------------------------------------
// temporal attention -> writes bf16 into padded layout
// ---------------------------------------------------------------------------
__global__ __launch_bounds__(256) void datt_kernel(
    const float* __restrict__ q, const float* __restrict__ k,
    const float* __restrict__ v, unsigned short* __restrict__ Dp)
{
    int t = blockIdx.x * 256 + threadIdx.x;
    int nc = t >> 8, hw = t & 255;
    int n = nc >> 6, c = nc & 63;
    size_t base = (size_t)nc * DHW + hw;

    float qv[8], kv[8], vv_[8];
#pragma unroll
    for (int d = 0; d < 8; ++d) {
        qv[d]  = q[base + d * HW];
        kv[d]  = k[base + d * HW];
        vv_[d] = v[base + d * HW];
    }
    float kmax = 0.f;
#pragma unroll
    for (int d = 0; d < 8; ++d) kmax = fmaxf(kmax, kv[d]);

    float wgt[8];
#pragma unroll
    for (int i = 0; i < 8; ++i) {
        float den = 0.f, qkm = qv[i] * kmax;
#pragma unroll
        for (int j = 0; j < 8; ++j)
            den += __expf(qv[i] * kv[j] - qkm);
        wgt[i] = vv_[i] / den;
    }
    int h = hw >> 4, w = hw & 15;
#pragma unroll
    for (int j = 0; j < 8; ++j) {
        float o = 0.f, kjm = kv[j] - kmax;
#pragma unroll
        for (int i = 0; i < 8; ++i)
            o += wgt[i] * __expf(qv[i] * kjm);
        size_t dst = ((((size_t)(n * 10 + j + 1) * 8 + (c >> 3)) * PG)
                      + (h + 1) * 18 + (w + 1)) * 8 + (c & 7);
        Dp[dst] = f2bf(o);
    }
}

// ---------------------------------------------------------------------------
// MFMA implicit-GEMM conv: one branch per block; tile 32co x 256pos (1 slice)
// grid = 2 branch x 16 cotile x 16 slice = 512 blocks, 256 thr = 4 waves.
// K = 27 taps x 64 ci, staged in two 32-ci halves.
// ---------------------------------------------------------------------------
__global__ __launch_bounds__(256, 2) void conv_mfma_kernel(
    const unsigned short* __restrict__ Pp, const unsigned short* __restrict__ Dp,
    const unsigned short* __restrict__ Wt,
    float* __restrict__ accS, float* __restrict__ accD)
{
    int bid = blockIdx.x;
    int s  = bid & 15;
    int ct = (bid >> 4) & 15;
    int b  = bid >> 8;
    int n = s >> 3, d = s & 7;

    const unsigned short* In = b ? Dp : Pp;
    const unsigned short* W  = Wt + (size_t)b * WTSZ;
    float* Acc = b ? accD : accS;

    __shared__ __align__(16) unsigned short lds[3 * 4 * GPLN];  // 62208 B

    int t = threadIdx.x;
    int wid = t >> 6, lane = t & 63;
    int l15 = lane & 15, l4 = lane >> 4;
    int hrow = wid * 4;

    f32x4 acc[2][4];
#pragma unroll
    for (int mt = 0; mt < 2; ++mt)
#pragma unroll
        for (int nt = 0; nt < 4; ++nt)
            acc[mt][nt] = (f32x4){0.f, 0.f, 0.f, 0.f};

    for (int half = 0; half < 2; ++half) {
        __syncthreads();
        // stage 3 planes x (4 g contiguous) = 20736 B each
#pragma unroll
        for (int dp = 0; dp < 3; ++dp) {
            const uint4* src = reinterpret_cast<const uint4*>(
                In + ((size_t)((n * 10 + d + dp) * 8 + half * 4)) * GPLN);
            uint4* dst = reinterpret_cast<uint4*>(lds) + dp * 1296;
#pragma unroll
            for (int it = 0; it < 6; ++it) {
                int idx = it * 256 + t;
                if (idx < 1296) dst[idx] = src[idx];
            }
        }
        __syncthreads();

        for (int tap = 0; tap < 27; ++tap) {
            int kd = tap / 9, kh = (tap % 9) / 3, kw = tap % 3;

            const unsigned short* wbase =
                W + ((size_t)tap * 512 + ct * 32 + l15) * 64 + half * 32 + l4 * 8;
            bf16x8 af0 = *reinterpret_cast<const bf16x8*>(wbase);
            bf16x8 af1 = *reinterpret_cast<const bf16x8*>(wbase + 16 * 64);

            bf16x8 bf[4];
#pragma unroll
            for (int nt = 0; nt < 4; ++nt) {
                int e = ((kd * 4 + l4) * PG + (hrow + nt + kh) * 18 + (l15 + kw)) * 8;
                bf[nt] = *reinterpret_cast<const bf16x8*>(&lds[e]);
            }
#pragma unroll
            for (int nt = 0; nt < 4; ++nt) {
                acc[0][nt] = __builtin_amdgcn_mfma_f32_16x16x32_bf16(
                    af0, bf[nt], acc[0][nt], 0, 0, 0);
                acc[1][nt] = __builtin_amdgcn_mfma_f32_16x16x32_bf16(
                    af1, bf[nt], acc[1][nt], 0, 0, 0);
            }
        }
    }

    // store: co = ct*32 + mt*16 + l4*4 + r ; pos = wid*64 + nt*16 + l15
#pragma unroll
    for (int mt = 0; mt < 2; ++mt) {
#pragma unroll
        for (int nt = 0; nt < 4; ++nt) {
#pragma unroll
            for (int r = 0; r < 4; ++r) {
                int co = ct * 32 + mt * 16 + l4 * 4 + r;
                int pos = wid * 64 + nt * 16 + l15;
                Acc[((size_t)(n * 512 + co)) * 2048 + d * 256 + pos] = acc[mt][nt][r];
            }
        }
    }
}

// ---------------------------------------------------------------------------
// epilogue: out = gama*(relu(BNs(aS)) + relu(BNd(aD))) + x
// ---------------------------------------------------------------------------
__global__ __launch_bounds__(256) void epilogue_kernel(
    const float* __restrict__ accS, const float* __restrict__ accD,
    const float* __restrict__ bs, const float* __restrict__ gs,
    const float* __restrict__ bts, const float* __restrict__ ms,
    const float* __restrict__ vs,
    const float* __restrict__ bd, const float* __restrict__ gd,
    const float* __restrict__ btd, const float* __restrict__ md,
    const float* __restrict__ vd,
    const float* __restrict__ x, const float* __restrict__ gama,
    float* __restrict__ out)
{
    int u = blockIdx.x * 256 + threadIdx.x;      // float4 index
    int co = (u & 262143) >> 9;

    float4 aS = reinterpret_cast<const float4*>(accS)[u];
    float4 aD = reinterpret_cast<const float4*>(accD)[u];
    float4 xv = reinterpret_cast<const float4*>(x)[u];

    float sS = gs[co] * rsqrtf(vs[co] + EPSBN);
    float oS = bs[co] - ms[co];
    float sD = gd[co] * rsqrtf(vd[co] + EPSBN);
    float oD = bd[co] - md[co];
    float g = gama[0];

    float4 o;
    o.x = g * (fmaxf((aS.x + oS) * sS + bts[co], 0.f) + fmaxf((aD.x + oD) * sD + btd[co], 0.f)) + xv.x;
    o.y = g * (fmaxf((aS.y + oS) * sS + bts[co], 0.f) + fmaxf((aD.y + oD) * sD + btd[co], 0.f)) + xv.y;
    o.z = g * (fmaxf((aS.z + oS) * sS + bts[co], 0.f) + fmaxf((aD.z + oD) * sD + btd[co], 0.f)) + xv.z;
    o.w = g * (fmaxf((aS.w + oS) * sS + bts[co], 0.f) + fmaxf((aD.w + oD) * sD + btd[co], 0.f)) + xv.w;
    reinterpret_cast<float4*>(out)[u] = o;
}

// ---------------------------------------------------------------------------
extern "C" void kernel_launch(void* const* d_in, const int* in_sizes, int n_in,
                              void* d_out, int out_size, void* d_ws, size_t ws_size,
                              hipStream_t stream)
{
    const float* x    = (const float*)d_in[0];
    const float* gama = (const float*)d_in[1];
    const float* Wq  = (const float*)d_in[2];
    const float* bq  = (const float*)d_in[3];
    const float* gq  = (const float*)d_in[4];
    const float* btq = (const float*)d_in[5];
    const float* mq  = (const float*)d_in[6];
    const float* vq  = (const float*)d_in[7];
    const float* Wk  = (const float*)d_in[8];
    const float* bk  = (const float*)d_in[9];
    const float* gk  = (const float*)d_in[10];
    const float* btk = (const float*)d_in[11];
    const float* mk  = (const float*)d_in[12];
    const float* vk  = (const float*)d_in[13];
    const float* Wv  = (const float*)d_in[14];
    const float* bv  = (const float*)d_in[15];
    const float* gv  = (const float*)d_in[16];
    const float* btv = (const float*)d_in[17];
    const float* mv  = (const float*)d_in[18];
    const float* vv  = (const float*)d_in[19];
    const float* Ws  = (const float*)d_in[20];
    const float* bs  = (const float*)d_in[21];
    const float* gs  = (const float*)d_in[22];
    const float* bts = (const float*)d_in[23];
    const float* ms  = (const float*)d_in[24];
    const float* vs  = (const float*)d_in[25];
    const float* Wd  = (const float*)d_in[26];
    const float* bd  = (const float*)d_in[27];
    const float* gd  = (const float*)d_in[28];
    const float* btd = (const float*)d_in[29];
    const float* md  = (const float*)d_in[30];
    const float* vd  = (const float*)d_in[31];

    char* ws = (char*)d_ws;
    unsigned short* Pp = (unsigned short*)ws;                       // 829440 B
    unsigned short* Dp = Pp + PADSZ;                                // 829440 B
    unsigned short* Wt = Dp + PADSZ;                                // 3538944 B
    float* q    = (float*)(ws + 5197824);
    float* k    = q + QSZ;
    float* v    = k + QSZ;
    float* accS = (float*)(ws + 8343552);
    float* accD = accS + 2 * 512 * 2048;

    // zero padded buffers (both, contiguous): 1658880 B = 103680 uint4
    zero_pads_kernel<<<405, 256, 0, stream>>>((uint4*)Pp);
    wtrans_kernel<<<1024, 256, 0, stream>>>(Ws, Wd, Wt);

    qkv_kernel<<<192, 256, 0, stream>>>(
        x,
        Wq, bq, gq, btq, mq, vq,
        Wk, bk, gk, btk, mk, vk,
        Wv, bv, gv, btv, mv, vv,
        q, k, v);

    patt_kernel<<<1024, 256, 0, stream>>>(q, k, v, Pp);
    datt_kernel<<<128, 256, 0, stream>>>(q, k, v, Dp);

    conv_mfma_kernel<<<512, 256, 0, stream>>>(Pp, Dp, Wt, accS, accD);

    epilogue_kernel<<<2048, 256, 0, stream>>>(
        accS, accD,
        bs, gs, bts, ms, vs,
        bd, gd, btd, md, vd,
        x, gama, (float*)d_out);
}

// Round 3
// 116.166 us; speedup vs baseline: 8.5924x; 1.5932x over previous
//
#include <hip/hip_runtime.h>
#include <cmath>

#define EPSBN 1e-5f

namespace {
constexpr int C_IN = 512;
constexpr int CC   = 64;
constexpr int CD   = 8;
constexpr int CH   = 16;
constexpr int CW   = 16;
constexpr int HW   = CH * CW;        // 256
constexpr int DHW  = CD * HW;        // 2048
constexpr int QSZ  = 2 * CC * DHW;   // 262144 floats per q/k/v buffer

// padded input layout for conv: [n 2][dp 10][g 8][row 18][col 18][cil 8] bf16
constexpr int PG    = 18 * 18;           // 324 positions per padded plane
constexpr int GPLN  = PG * 8;            // 2592 elems per (dp,g) plane
constexpr int PADSZ = 2 * 10 * 8 * GPLN; // 414720 elems per branch
// Wt layout: [branch][tap 27][co 512][ci 64] bf16
constexpr int WTSZ  = 27 * 512 * 64;     // per branch elems

typedef __attribute__((ext_vector_type(8))) short bf16x8;
typedef __attribute__((ext_vector_type(4))) float f32x4;

__device__ inline unsigned short f2bf(float f) {
    unsigned u = __float_as_uint(f);
    return (unsigned short)((u + 0x7fffu + ((u >> 16) & 1u)) >> 16);
}
}

// ---------------------------------------------------------------------------
// zero the padded P/D buffers (borders must be 0 every call)
// ---------------------------------------------------------------------------
__global__ __launch_bounds__(256) void zero_pads_kernel(uint4* __restrict__ p)
{
    p[blockIdx.x * 256 + threadIdx.x] = make_uint4(0, 0, 0, 0);
}

// ---------------------------------------------------------------------------
// weight transpose: W[co][ci][27] fp32 -> Wt[branch][tap][co][ci] bf16
// ---------------------------------------------------------------------------
__global__ __launch_bounds__(256) void wtrans_kernel(
    const float* __restrict__ Ws, const float* __restrict__ Wd,
    unsigned short* __restrict__ Wt)
{
    int b  = blockIdx.x >> 9;
    int co = blockIdx.x & 511;
    const float* W = b ? Wd : Ws;
    unsigned short* o = Wt + (size_t)b * WTSZ;
    for (int k = threadIdx.x; k < 27 * 64; k += 256) {
        int tap = k >> 6, ci = k & 63;
        float w = W[((size_t)co * 64 + ci) * 27 + tap];
        o[((size_t)tap * 512 + co) * 64 + ci] = f2bf(w);
    }
}

// ---------------------------------------------------------------------------
// stack Wq/Wk/Wv -> Wqkv[192co][512ci] bf16
// ---------------------------------------------------------------------------
__global__ __launch_bounds__(256) void wqkv_prep_kernel(
    const float* __restrict__ Wq, const float* __restrict__ Wk,
    const float* __restrict__ Wv, unsigned short* __restrict__ Wqkv)
{
    int co = blockIdx.x;                 // 0..191
    const float* W = co < 64 ? Wq : co < 128 ? Wk : Wv;
    int c = co & 63;
    for (int ci = threadIdx.x; ci < 512; ci += 256)
        Wqkv[(size_t)co * 512 + ci] = f2bf(W[(size_t)c * 512 + ci]);
}

// ---------------------------------------------------------------------------
// fused transpose + MFMA GEMM for q/k/v:
//   C[192co][4096pos] = Wqkv[192][512] * Xt[512][4096], then BN+ReLU.
// grid = 128 blocks (32-pos tiles); block = 256 thr = 4 waves.
// LDS: x-tile [32 pos][512 ci] bf16, XOR-swizzled 16B granules.
// wave (wid>>1) -> pos half (16 pos), (wid&1) -> 6 of 12 co-fragments.
// ---------------------------------------------------------------------------
__global__ __launch_bounds__(256) void qkv_gemm_kernel(
    const float* __restrict__ x, const unsigned short* __restrict__ Wqkv,
    const float* __restrict__ bq, const float* __restrict__ gq,
    const float* __restrict__ btq, const float* __restrict__ mq,
    const float* __restrict__ vq,
    const float* __restrict__ bk, const float* __restrict__ gk,
    const float* __restrict__ btk, const float* __restrict__ mk,
    const float* __restrict__ vk,
    const float* __restrict__ bv, const float* __restrict__ gv,
    const float* __restrict__ btv, const float* __restrict__ mv,
    const float* __restrict__ vv,
    float* __restrict__ outq, float* __restrict__ outk, float* __restrict__ outv)
{
    int bid = blockIdx.x;
    int n = bid >> 6, p0 = (bid & 63) * 32;

    __shared__ __align__(16) unsigned short xs[32 * 512];   // 32 KB, swizzled
    int t = threadIdx.x;

    // ---- stage + transpose + bf16 convert ----
    const float* xb = x + ((size_t)n * C_IN) * DHW + p0;
#pragma unroll
    for (int pass = 0; pass < 16; ++pass) {
        int ci = pass * 32 + (t >> 3);
        int pb = (t & 7) * 4;
        float4 v4 = *reinterpret_cast<const float4*>(xb + (size_t)ci * DHW + pb);
        float arr[4] = {v4.x, v4.y, v4.z, v4.w};
#pragma unroll
        for (int u = 0; u < 4; ++u) {
            int pos = pb + u;
            int boff = pos * 1024 + ((ci * 2) ^ ((pos & 7) << 4));
            *reinterpret_cast<unsigned short*>(
                reinterpret_cast<char*>(xs) + boff) = f2bf(arr[u]);
        }
    }
    __syncthreads();

    // ---- GEMM ----
    int wid = t >> 6, lane = t & 63;
    int l15 = lane & 15, l4 = lane >> 4;
    int wbase = (wid >> 1) * 16;
    int mh = (wid & 1) * 6;
    int pos = wbase + l15;

    bf16x8 bfr[16];
    const char* xsb = reinterpret_cast<const char*>(xs) + pos * 1024;
    int swz = (pos & 7) << 4;
#pragma unroll
    for (int kk = 0; kk < 16; ++kk)
        bfr[kk] = *reinterpret_cast<const bf16x8*>(xsb + ((kk * 64 + l4 * 16) ^ swz));

    f32x4 acc[6];
#pragma unroll
    for (int i = 0; i < 6; ++i) acc[i] = (f32x4){0.f, 0.f, 0.f, 0.f};

#pragma unroll
    for (int i = 0; i < 6; ++i) {
        const unsigned short* wrow =
            Wqkv + ((size_t)(mh + i) * 16 + l15) * 512 + l4 * 8;
#pragma unroll
        for (int kk = 0; kk < 16; ++kk) {
            bf16x8 af = *reinterpret_cast<const bf16x8*>(wrow + kk * 32);
            acc[i] = __builtin_amdgcn_mfma_f32_16x16x32_bf16(af, bfr[kk], acc[i], 0, 0, 0);
        }
    }

    // ---- BN + ReLU epilogue ----
#pragma unroll
    for (int i = 0; i < 6; ++i) {
        int mf = mh + i;
        int br = mf >> 2;                    // 0=q 1=k 2=v
        const float* bb  = br == 0 ? bq  : br == 1 ? bk  : bv;
        const float* gg  = br == 0 ? gq  : br == 1 ? gk  : gv;
        const float* bt  = br == 0 ? btq : br == 1 ? btk : btv;
        const float* mm  = br == 0 ? mq  : br == 1 ? mk  : mv;
        const float* vvp = br == 0 ? vq  : br == 1 ? vk  : vv;
        float*       op  = br == 0 ? outq : br == 1 ? outk : outv;
        int cb = (mf & 3) * 16 + l4 * 4;
#pragma unroll
        for (int r = 0; r < 4; ++r) {
            int c = cb + r;
            float s = gg[c] * rsqrtf(vvp[c] + EPSBN);
            float val = (acc[i][r] + bb[c] - mm[c]) * s + bt[c];
            op[((size_t)(n * CC + c)) * DHW + p0 + pos] = fmaxf(val, 0.f);
        }
    }
}

// ---------------------------------------------------------------------------
// spatial attention -> writes bf16 into padded layout
// ---------------------------------------------------------------------------
__global__ __launch_bounds__(256) void patt_kernel(
    const float* __restrict__ q, const float* __restrict__ k,
    const float* __restrict__ v, unsigned short* __restrict__ Pp)
{
    int b = blockIdx.x;            // (n,c,d)
    int n = b >> 9, c = (b >> 3) & 63, d = b & 7;
    size_t base = (size_t)b * HW;
    __shared__ float sk[256], sq[256], sw[256];
    int t = threadIdx.x;
    float kt = k[base + t];
    float qt = q[base + t];
    float vt = v[base + t];
    sk[t] = kt;
    sq[t] = qt;
    __syncthreads();

    float kmax = 0.f;
    for (int j = 0; j < 256; ++j) kmax = fmaxf(kmax, sk[j]);

    float den = 0.f;
    float qkm = qt * kmax;
    for (int j = 0; j < 256; ++j)
        den += __expf(qt * sk[j] - qkm);
    sw[t] = vt / den;
    __syncthreads();

    float kjm = kt - kmax;
    float o = 0.f;
    for (int i = 0; i < 256; ++i)
        o += sw[i] * __expf(sq[i] * kjm);

    int h = t >> 4, w = t & 15;
    size_t dst = ((((size_t)(n * 10 + d + 1) * 8 + (c >> 3)) * PG)
                  + (h + 1) * 18 + (w + 1)) * 8 + (c & 7);
    Pp[dst] = f2bf(o);
}

// ---------------------------------------------------------------------------
// temporal attention -> writes bf16 into padded layout
// ---------------------------------------------------------------------------
__global__ __launch_bounds__(256) void datt_kernel(
    const float* __restrict__ q, const float* __restrict__ k,
    const float* __restrict__ v, unsigned short* __restrict__ Dp)
{
    int t = blockIdx.x * 256 + threadIdx.x;
    int nc = t >> 8, hw = t & 255;
    int n = nc >> 6, c = nc & 63;
    size_t base = (size_t)nc * DHW + hw;

    float qv[8], kv[8], vv_[8];
#pragma unroll
    for (int d = 0; d < 8; ++d) {
        qv[d]  = q[base + d * HW];
        kv[d]  = k[base + d * HW];
        vv_[d] = v[base + d * HW];
    }
    float kmax = 0.f;
#pragma unroll
    for (int d = 0; d < 8; ++d) kmax = fmaxf(kmax, kv[d]);

    float wgt[8];
#pragma unroll
    for (int i = 0; i < 8; ++i) {
        float den = 0.f, qkm = qv[i] * kmax;
#pragma unroll
        for (int j = 0; j < 8; ++j)
            den += __expf(qv[i] * kv[j] - qkm);
        wgt[i] = vv_[i] / den;
    }
    int h = hw >> 4, w = hw & 15;
#pragma unroll
    for (int j = 0; j < 8; ++j) {
        float o = 0.f, kjm = kv[j] - kmax;
#pragma unroll
        for (int i = 0; i < 8; ++i)
            o += wgt[i] * __expf(qv[i] * kjm);
        size_t dst = ((((size_t)(n * 10 + j + 1) * 8 + (c >> 3)) * PG)
                      + (h + 1) * 18 + (w + 1)) * 8 + (c & 7);
        Dp[dst] = f2bf(o);
    }
}

// ---------------------------------------------------------------------------
// MFMA implicit-GEMM conv: one branch per block; tile 32co x 256pos (1 slice)
// grid = 2 branch x 16 cotile x 16 slice = 512 blocks, 256 thr = 4 waves.
// K = 27 taps x 64 ci, staged in two 32-ci halves.
// ---------------------------------------------------------------------------
__global__ __launch_bounds__(256, 2) void conv_mfma_kernel(
    const unsigned short* __restrict__ Pp, const unsigned short* __restrict__ Dp,
    const unsigned short* __restrict__ Wt,
    float* __restrict__ accS, float* __restrict__ accD)
{
    int bid = blockIdx.x;
    int s  = bid & 15;
    int ct = (bid >> 4) & 15;
    int b  = bid >> 8;
    int n = s >> 3, d = s & 7;

    const unsigned short* In = b ? Dp : Pp;
    const unsigned short* W  = Wt + (size_t)b * WTSZ;
    float* Acc = b ? accD : accS;

    __shared__ __align__(16) unsigned short lds[3 * 4 * GPLN];  // 62208 B

    int t = threadIdx.x;
    int wid = t >> 6, lane = t & 63;
    int l15 = lane & 15, l4 = lane >> 4;
    int hrow = wid * 4;

    f32x4 acc[2][4];
#pragma unroll
    for (int mt = 0; mt < 2; ++mt)
#pragma unroll
        for (int nt = 0; nt < 4; ++nt)
            acc[mt][nt] = (f32x4){0.f, 0.f, 0.f, 0.f};

    for (int half = 0; half < 2; ++half) {
        __syncthreads();
#pragma unroll
        for (int dp = 0; dp < 3; ++dp) {
            const uint4* src = reinterpret_cast<const uint4*>(
                In + ((size_t)((n * 10 + d + dp) * 8 + half * 4)) * GPLN);
            uint4* dst = reinterpret_cast<uint4*>(lds) + dp * 1296;
#pragma unroll
            for (int it = 0; it < 6; ++it) {
                int idx = it * 256 + t;
                if (idx < 1296) dst[idx] = src[idx];
            }
        }
        __syncthreads();

        for (int tap = 0; tap < 27; ++tap) {
            int kd = tap / 9, kh = (tap % 9) / 3, kw = tap % 3;

            const unsigned short* wbase =
                W + ((size_t)tap * 512 + ct * 32 + l15) * 64 + half * 32 + l4 * 8;
            bf16x8 af0 = *reinterpret_cast<const bf16x8*>(wbase);
            bf16x8 af1 = *reinterpret_cast<const bf16x8*>(wbase + 16 * 64);

            bf16x8 bf[4];
#pragma unroll
            for (int nt = 0; nt < 4; ++nt) {
                int e = ((kd * 4 + l4) * PG + (hrow + nt + kh) * 18 + (l15 + kw)) * 8;
                bf[nt] = *reinterpret_cast<const bf16x8*>(&lds[e]);
            }
#pragma unroll
            for (int nt = 0; nt < 4; ++nt) {
                acc[0][nt] = __builtin_amdgcn_mfma_f32_16x16x32_bf16(
                    af0, bf[nt], acc[0][nt], 0, 0, 0);
                acc[1][nt] = __builtin_amdgcn_mfma_f32_16x16x32_bf16(
                    af1, bf[nt], acc[1][nt], 0, 0, 0);
            }
        }
    }

#pragma unroll
    for (int mt = 0; mt < 2; ++mt) {
#pragma unroll
        for (int nt = 0; nt < 4; ++nt) {
#pragma unroll
            for (int r = 0; r < 4; ++r) {
                int co = ct * 32 + mt * 16 + l4 * 4 + r;
                int pos = wid * 64 + nt * 16 + l15;
                Acc[((size_t)(n * 512 + co)) * 2048 + d * 256 + pos] = acc[mt][nt][r];
            }
        }
    }
}

// ---------------------------------------------------------------------------
// epilogue: out = gama*(relu(BNs(aS)) + relu(BNd(aD))) + x
// ---------------------------------------------------------------------------
__global__ __launch_bounds__(256) void epilogue_kernel(
    const float* __restrict__ accS, const float* __restrict__ accD,
    const float* __restrict__ bs, const float* __restrict__ gs,
    const float* __restrict__ bts, const float* __restrict__ ms,
    const float* __restrict__ vs,
    const float* __restrict__ bd, const float* __restrict__ gd,
    const float* __restrict__ btd, const float* __restrict__ md,
    const float* __restrict__ vd,
    const float* __restrict__ x, const float* __restrict__ gama,
    float* __restrict__ out)
{
    int u = blockIdx.x * 256 + threadIdx.x;      // float4 index
    int co = (u & 262143) >> 9;

    float4 aS = reinterpret_cast<const float4*>(accS)[u];
    float4 aD = reinterpret_cast<const float4*>(accD)[u];
    float4 xv = reinterpret_cast<const float4*>(x)[u];

    float sS = gs[co] * rsqrtf(vs[co] + EPSBN);
    float oS = bs[co] - ms[co];
    float sD = gd[co] * rsqrtf(vd[co] + EPSBN);
    float oD = bd[co] - md[co];
    float g = gama[0];

    float4 o;
    o.x = g * (fmaxf((aS.x + oS) * sS + bts[co], 0.f) + fmaxf((aD.x + oD) * sD + btd[co], 0.f)) + xv.x;
    o.y = g * (fmaxf((aS.y + oS) * sS + bts[co], 0.f) + fmaxf((aD.y + oD) * sD + btd[co], 0.f)) + xv.y;
    o.z = g * (fmaxf((aS.z + oS) * sS + bts[co], 0.f) + fmaxf((aD.z + oD) * sD + btd[co], 0.f)) + xv.z;
    o.w = g * (fmaxf((aS.w + oS) * sS + bts[co], 0.f) + fmaxf((aD.w + oD) * sD + btd[co], 0.f)) + xv.w;
    reinterpret_cast<float4*>(out)[u] = o;
}

// ---------------------------------------------------------------------------
extern "C" void kernel_launch(void* const* d_in, const int* in_sizes, int n_in,
                              void* d_out, int out_size, void* d_ws, size_t ws_size,
                              hipStream_t stream)
{
    const float* x    = (const float*)d_in[0];
    const float* gama = (const float*)d_in[1];
    const float* Wq  = (const float*)d_in[2];
    const float* bq  = (const float*)d_in[3];
    const float* gq  = (const float*)d_in[4];
    const float* btq = (const float*)d_in[5];
    const float* mq  = (const float*)d_in[6];
    const float* vq  = (const float*)d_in[7];
    const float* Wk  = (const float*)d_in[8];
    const float* bk  = (const float*)d_in[9];
    const float* gk  = (const float*)d_in[10];
    const float* btk = (const float*)d_in[11];
    const float* mk  = (const float*)d_in[12];
    const float* vk  = (const float*)d_in[13];
    const float* Wv  = (const float*)d_in[14];
    const float* bv  = (const float*)d_in[15];
    const float* gv  = (const float*)d_in[16];
    const float* btv = (const float*)d_in[17];
    const float* mv  = (const float*)d_in[18];
    const float* vv  = (const float*)d_in[19];
    const float* Ws  = (const float*)d_in[20];
    const float* bs  = (const float*)d_in[21];
    const float* gs  = (const float*)d_in[22];
    const float* bts = (const float*)d_in[23];
    const float* ms  = (const float*)d_in[24];
    const float* vs  = (const float*)d_in[25];
    const float* Wd  = (const float*)d_in[26];
    const float* bd  = (const float*)d_in[27];
    const float* gd  = (const float*)d_in[28];
    const float* btd = (const float*)d_in[29];
    const float* md  = (const float*)d_in[30];
    const float* vd  = (const float*)d_in[31];

    char* ws = (char*)d_ws;
    unsigned short* Pp = (unsigned short*)ws;                       // 829440 B
    unsigned short* Dp = Pp + PADSZ;                                // 829440 B
    unsigned short* Wt = Dp + PADSZ;                                // 3538944 B
    float* q    = (float*)(ws + 5197824);
    float* k    = q + QSZ;
    float* v    = k + QSZ;
    float* accS = (float*)(ws + 8343552);
    float* accD = accS + 2 * 512 * 2048;
    // Wqkv aliases the start of accS: consumed by qkv_gemm BEFORE conv_mfma
    // overwrites accS, and rewritten by wqkv_prep every call. Deterministic.
    unsigned short* Wqkv = (unsigned short*)accS;

    zero_pads_kernel<<<405, 256, 0, stream>>>((uint4*)Pp);
    wtrans_kernel<<<1024, 256, 0, stream>>>(Ws, Wd, Wt);
    wqkv_prep_kernel<<<192, 256, 0, stream>>>(Wq, Wk, Wv, Wqkv);

    qkv_gemm_kernel<<<128, 256, 0, stream>>>(
        x, Wqkv,
        bq, gq, btq, mq, vq,
        bk, gk, btk, mk, vk,
        bv, gv, btv, mv, vv,
        q, k, v);

    patt_kernel<<<1024, 256, 0, stream>>>(q, k, v, Pp);
    datt_kernel<<<128, 256, 0, stream>>>(q, k, v, Dp);

    conv_mfma_kernel<<<512, 256, 0, stream>>>(Pp, Dp, Wt, accS, accD);

    epilogue_kernel<<<2048, 256, 0, stream>>>(
        accS, accD,
        bs, gs, bts, ms, vs,
        bd, gd, btd, md, vd,
        x, gama, (float*)d_out);
}

// Round 5
// 97.218 us; speedup vs baseline: 10.2671x; 1.1949x over previous
//
#include <hip/hip_runtime.h>
#include <cmath>

#define EPSBN 1e-5f

namespace {
constexpr int C_IN = 512;
constexpr int CC   = 64;
constexpr int CD   = 8;
constexpr int HW   = 256;
constexpr int DHW  = CD * HW;        // 2048
constexpr int QSZ  = 2 * CC * DHW;   // 262144 floats per q/k/v buffer

// padded input layout for conv: [n 2][dp 10][g 8][row 18][col 18][cil 8] bf16
constexpr int PG    = 18 * 18;           // 324
constexpr int GPLN  = PG * 8;            // 2592 elems per (dp,g) plane
constexpr int PADSZ = 2 * 10 * 8 * GPLN; // 414720 elems per branch
// Wt layout: [branch][tap 27][co 512][ci 64] bf16
constexpr int WTSZ  = 27 * 512 * 64;

typedef __attribute__((ext_vector_type(8))) short bf16x8;
typedef __attribute__((ext_vector_type(4))) float f32x4;

__device__ inline unsigned short f2bf(float f) {
    unsigned u = __float_as_uint(f);
    return (unsigned short)((u + 0x7fffu + ((u >> 16) & 1u)) >> 16);
}
}

// ---------------------------------------------------------------------------
// prep: [0,405) zero pads | [405,1429) weight transpose | [1429,1621) Wqkv
// ---------------------------------------------------------------------------
__global__ __launch_bounds__(256) void prep_kernel(
    const float* __restrict__ Ws, const float* __restrict__ Wd,
    const float* __restrict__ Wq, const float* __restrict__ Wk,
    const float* __restrict__ Wv,
    uint4* __restrict__ pads, unsigned short* __restrict__ Wt,
    unsigned short* __restrict__ Wqkv)
{
    int bid = blockIdx.x;
    int t = threadIdx.x;
    if (bid < 405) {
        pads[bid * 256 + t] = make_uint4(0, 0, 0, 0);
    } else if (bid < 1429) {
        int b2 = bid - 405;
        int b  = b2 >> 9;
        int co = b2 & 511;
        const float* W = b ? Wd : Ws;
        unsigned short* o = Wt + (size_t)b * WTSZ;
        for (int k = t; k < 27 * 64; k += 256) {
            int tap = k >> 6, ci = k & 63;
            float w = W[((size_t)co * 64 + ci) * 27 + tap];
            o[((size_t)tap * 512 + co) * 64 + ci] = f2bf(w);
        }
    } else {
        int co = bid - 1429;          // 0..191
        const float* W = co < 64 ? Wq : co < 128 ? Wk : Wv;
        int c = co & 63;
        for (int ci = t; ci < 512; ci += 256)
            Wqkv[(size_t)co * 512 + ci] = f2bf(W[(size_t)c * 512 + ci]);
    }
}

// ---------------------------------------------------------------------------
// fused transpose + MFMA GEMM for q/k/v (+BN+ReLU).
// grid = 256 (2 n x 128 pos-tiles of 16); block 256 thr = 4 waves.
// LDS: [16 pos][512 ci] bf16, XOR-swizzled 16B granules.
// wave w owns 3 co-frags (12 total = 192 co).
// ---------------------------------------------------------------------------
__global__ __launch_bounds__(256) void qkv_gemm_kernel(
    const float* __restrict__ x, const unsigned short* __restrict__ Wqkv,
    const float* __restrict__ bq, const float* __restrict__ gq,
    const float* __restrict__ btq, const float* __restrict__ mq,
    const float* __restrict__ vq,
    const float* __restrict__ bk, const float* __restrict__ gk,
    const float* __restrict__ btk, const float* __restrict__ mk,
    const float* __restrict__ vk,
    const float* __restrict__ bv, const float* __restrict__ gv,
    const float* __restrict__ btv, const float* __restrict__ mv,
    const float* __restrict__ vv,
    float* __restrict__ outq, float* __restrict__ outk, float* __restrict__ outv)
{
    int bid = blockIdx.x;
    int n = bid >> 7, p0 = (bid & 127) * 16;

    __shared__ __align__(16) unsigned short xs[16 * 512];   // 16 KB
    int t = threadIdx.x;

    const float* xb = x + ((size_t)n * C_IN) * DHW + p0;
#pragma unroll
    for (int pass = 0; pass < 8; ++pass) {
        int idx = pass * 256 + t;          // 0..2047
        int ci = idx >> 2, pq = idx & 3;
        float4 v4 = *reinterpret_cast<const float4*>(xb + (size_t)ci * DHW + pq * 4);
        float arr[4] = {v4.x, v4.y, v4.z, v4.w};
#pragma unroll
        for (int u = 0; u < 4; ++u) {
            int pos = pq * 4 + u;
            int boff = pos * 1024 + ((ci * 2) ^ ((pos & 7) << 4));
            *reinterpret_cast<unsigned short*>(
                reinterpret_cast<char*>(xs) + boff) = f2bf(arr[u]);
        }
    }
    __syncthreads();

    int wid = t >> 6, lane = t & 63;
    int l15 = lane & 15, l4 = lane >> 4;
    int mh = wid * 3;
    int pos = l15;

    bf16x8 bfr[16];
    const char* xsb = reinterpret_cast<const char*>(xs) + pos * 1024;
    int swz = (pos & 7) << 4;
#pragma unroll
    for (int kk = 0; kk < 16; ++kk)
        bfr[kk] = *reinterpret_cast<const bf16x8*>(xsb + ((kk * 64 + l4 * 16) ^ swz));

    f32x4 acc[3];
#pragma unroll
    for (int i = 0; i < 3; ++i) acc[i] = (f32x4){0.f, 0.f, 0.f, 0.f};

#pragma unroll
    for (int i = 0; i < 3; ++i) {
        const unsigned short* wrow =
            Wqkv + ((size_t)(mh + i) * 16 + l15) * 512 + l4 * 8;
#pragma unroll
        for (int kk = 0; kk < 16; ++kk) {
            bf16x8 af = *reinterpret_cast<const bf16x8*>(wrow + kk * 32);
            acc[i] = __builtin_amdgcn_mfma_f32_16x16x32_bf16(af, bfr[kk], acc[i], 0, 0, 0);
        }
    }

#pragma unroll
    for (int i = 0; i < 3; ++i) {
        int mf = mh + i;
        int br = mf >> 2;
        const float* bb  = br == 0 ? bq  : br == 1 ? bk  : bv;
        const float* gg  = br == 0 ? gq  : br == 1 ? gk  : gv;
        const float* bt  = br == 0 ? btq : br == 1 ? btk : btv;
        const float* mm  = br == 0 ? mq  : br == 1 ? mk  : mv;
        const float* vvp = br == 0 ? vq  : br == 1 ? vk  : vv;
        float*       op  = br == 0 ? outq : br == 1 ? outk : outv;
        int cb = (mf & 3) * 16 + l4 * 4;
#pragma unroll
        for (int r = 0; r < 4; ++r) {
            int c = cb + r;
            float s = gg[c] * rsqrtf(vvp[c] + EPSBN);
            float val = (acc[i][r] + bb[c] - mm[c]) * s + bt[c];
            op[((size_t)(n * CC + c)) * DHW + p0 + pos] = fmaxf(val, 0.f);
        }
    }
}

// ---------------------------------------------------------------------------
// attention (merged): blocks [0,1024) = spatial patt; [1024,1152) = datt.
// ---------------------------------------------------------------------------
__global__ __launch_bounds__(256) void att_kernel(
    const float* __restrict__ q, const float* __restrict__ k,
    const float* __restrict__ v,
    unsigned short* __restrict__ Pp, unsigned short* __restrict__ Dp)
{
    __shared__ float sk[256], sq[256], sw[256], red[4];
    int t = threadIdx.x;
    int bid = blockIdx.x;

    if (bid < 1024) {
        // ---- spatial attention over HW=256 for slice (n,c,d) ----
        int n = bid >> 9, c = (bid >> 3) & 63, d = bid & 7;
        size_t base = (size_t)bid * HW;
        float kt = k[base + t];
        float qt = q[base + t];
        float vt = v[base + t];
        sk[t] = kt;
        sq[t] = qt;

        // parallel block max of k (k >= 0)
        float m = kt;
#pragma unroll
        for (int off = 32; off >= 1; off >>= 1)
            m = fmaxf(m, __shfl_xor(m, off));
        if ((t & 63) == 0) red[t >> 6] = m;
        __syncthreads();
        float kmax = fmaxf(fmaxf(red[0], red[1]), fmaxf(red[2], red[3]));

        float qkm = qt * kmax;
        float d0 = 0.f, d1 = 0.f, d2 = 0.f, d3 = 0.f;
        for (int j = 0; j < 256; j += 4) {
            d0 += __expf(fmaf(qt, sk[j + 0], -qkm));
            d1 += __expf(fmaf(qt, sk[j + 1], -qkm));
            d2 += __expf(fmaf(qt, sk[j + 2], -qkm));
            d3 += __expf(fmaf(qt, sk[j + 3], -qkm));
        }
        float den = (d0 + d1) + (d2 + d3);
        sw[t] = vt / den;
        __syncthreads();

        float kjm = kt - kmax;
        float o0 = 0.f, o1 = 0.f, o2 = 0.f, o3 = 0.f;
        for (int i = 0; i < 256; i += 4) {
            o0 += sw[i + 0] * __expf(sq[i + 0] * kjm);
            o1 += sw[i + 1] * __expf(sq[i + 1] * kjm);
            o2 += sw[i + 2] * __expf(sq[i + 2] * kjm);
            o3 += sw[i + 3] * __expf(sq[i + 3] * kjm);
        }
        float o = (o0 + o1) + (o2 + o3);

        int h = t >> 4, w = t & 15;
        size_t dst = ((((size_t)(n * 10 + d + 1) * 8 + (c >> 3)) * PG)
                      + (h + 1) * 18 + (w + 1)) * 8 + (c & 7);
        Pp[dst] = f2bf(o);
    } else {
        // ---- temporal attention over D=8 per (n,c,h,w) ----
        int g = (bid - 1024) * 256 + t;
        int nc = g >> 8, hw = g & 255;
        int n = nc >> 6, c = nc & 63;
        size_t base = (size_t)nc * DHW + hw;

        float qv[8], kv[8], vv_[8];
#pragma unroll
        for (int d = 0; d < 8; ++d) {
            qv[d]  = q[base + d * HW];
            kv[d]  = k[base + d * HW];
            vv_[d] = v[base + d * HW];
        }
        float kmax = 0.f;
#pragma unroll
        for (int d = 0; d < 8; ++d) kmax = fmaxf(kmax, kv[d]);

        float wgt[8];
#pragma unroll
        for (int i = 0; i < 8; ++i) {
            float den = 0.f, qkm = qv[i] * kmax;
#pragma unroll
            for (int j = 0; j < 8; ++j)
                den += __expf(fmaf(qv[i], kv[j], -qkm));
            wgt[i] = vv_[i] / den;
        }
        int h = hw >> 4, w = hw & 15;
#pragma unroll
        for (int j = 0; j < 8; ++j) {
            float o = 0.f, kjm = kv[j] - kmax;
#pragma unroll
            for (int i = 0; i < 8; ++i)
                o += wgt[i] * __expf(qv[i] * kjm);
            size_t dst = ((((size_t)(n * 10 + j + 1) * 8 + (c >> 3)) * PG)
                          + (h + 1) * 18 + (w + 1)) * 8 + (c & 7);
            Dp[dst] = f2bf(o);
        }
    }
}

// ---------------------------------------------------------------------------
// fused dual-branch MFMA conv + BN + ReLU + gama*(a+b) + x.
// grid = 256 blocks = 16 co-tiles(32co) x 16 slices; 4 waves.
// 4 phases: (branch, ci-half); per kd: 18 hoisted B-granules reused 2x.
// ---------------------------------------------------------------------------
__global__ __launch_bounds__(256) void conv_fused_kernel(
    const unsigned short* __restrict__ Pp, const unsigned short* __restrict__ Dp,
    const unsigned short* __restrict__ Wt,
    const float* __restrict__ bs, const float* __restrict__ gs,
    const float* __restrict__ bts, const float* __restrict__ ms,
    const float* __restrict__ vs,
    const float* __restrict__ bd, const float* __restrict__ gd,
    const float* __restrict__ btd, const float* __restrict__ md,
    const float* __restrict__ vd,
    const float* __restrict__ x, const float* __restrict__ gama,
    float* __restrict__ out)
{
    int bid = blockIdx.x;
    int s  = bid & 15;
    int ct = bid >> 4;            // 0..15
    int n = s >> 3, d = s & 7;

    __shared__ __align__(16) unsigned short lds[3 * 4 * GPLN];  // 62208 B

    int t = threadIdx.x;
    int wid = t >> 6, lane = t & 63;
    int l15 = lane & 15, l4 = lane >> 4;
    int hrow = wid * 4;

    f32x4 acc[2][2][4];   // [branch][mt][nt]
#pragma unroll
    for (int b = 0; b < 2; ++b)
#pragma unroll
        for (int mt = 0; mt < 2; ++mt)
#pragma unroll
            for (int nt = 0; nt < 4; ++nt)
                acc[b][mt][nt] = (f32x4){0.f, 0.f, 0.f, 0.f};

#pragma unroll
    for (int phase = 0; phase < 4; ++phase) {
        int br = phase >> 1, half = phase & 1;
        const unsigned short* In = br ? Dp : Pp;
        __syncthreads();
#pragma unroll
        for (int dp = 0; dp < 3; ++dp) {
            const uint4* src = reinterpret_cast<const uint4*>(
                In + ((size_t)((n * 10 + d + dp) * 8 + half * 4)) * GPLN);
            uint4* dst = reinterpret_cast<uint4*>(lds) + dp * 1296;
#pragma unroll
            for (int it = 0; it < 6; ++it) {
                int idx = it * 256 + t;
                if (idx < 1296) dst[idx] = src[idx];
            }
        }
        __syncthreads();

        const unsigned short* W = Wt + (size_t)br * WTSZ;
#pragma unroll
        for (int kd = 0; kd < 3; ++kd) {
            bf16x8 g[6][3];
#pragma unroll
            for (int row = 0; row < 6; ++row)
#pragma unroll
                for (int kw = 0; kw < 3; ++kw)
                    g[row][kw] = *reinterpret_cast<const bf16x8*>(
                        &lds[(((kd * 4 + l4) * PG) + (hrow + row) * 18 + (l15 + kw)) * 8]);

#pragma unroll
            for (int kh = 0; kh < 3; ++kh) {
#pragma unroll
                for (int kw = 0; kw < 3; ++kw) {
                    int tap = (kd * 3 + kh) * 3 + kw;
                    const unsigned short* wb =
                        W + ((size_t)tap * 512 + ct * 32 + l15) * 64 + half * 32 + l4 * 8;
                    bf16x8 af0 = *reinterpret_cast<const bf16x8*>(wb);
                    bf16x8 af1 = *reinterpret_cast<const bf16x8*>(wb + 16 * 64);
#pragma unroll
                    for (int nt = 0; nt < 4; ++nt) {
                        acc[br][0][nt] = __builtin_amdgcn_mfma_f32_16x16x32_bf16(
                            af0, g[nt + kh][kw], acc[br][0][nt], 0, 0, 0);
                        acc[br][1][nt] = __builtin_amdgcn_mfma_f32_16x16x32_bf16(
                            af1, g[nt + kh][kw], acc[br][1][nt], 0, 0, 0);
                    }
                }
            }
        }
    }

    // fused epilogue
    float gm = gama[0];
#pragma unroll
    for (int mt = 0; mt < 2; ++mt) {
#pragma unroll
        for (int r = 0; r < 4; ++r) {
            int co = ct * 32 + mt * 16 + l4 * 4 + r;
            float sS = gs[co] * rsqrtf(vs[co] + EPSBN);
            float oS = bs[co] - ms[co];
            float tS = bts[co];
            float sD = gd[co] * rsqrtf(vd[co] + EPSBN);
            float oD = bd[co] - md[co];
            float tD = btd[co];
#pragma unroll
            for (int nt = 0; nt < 4; ++nt) {
                int pos = wid * 64 + nt * 16 + l15;
                size_t oi = ((size_t)(n * 512 + co)) * 2048 + d * 256 + pos;
                float rp = fmaxf((acc[0][mt][nt][r] + oS) * sS + tS, 0.f);
                float rd = fmaxf((acc[1][mt][nt][r] + oD) * sD + tD, 0.f);
                out[oi] = gm * (rp + rd) + x[oi];
            }
        }
    }
}

// ---------------------------------------------------------------------------
extern "C" void kernel_launch(void* const* d_in, const int* in_sizes, int n_in,
                              void* d_out, int out_size, void* d_ws, size_t ws_size,
                              hipStream_t stream)
{
    const float* x    = (const float*)d_in[0];
    const float* gama = (const float*)d_in[1];
    const float* Wq  = (const float*)d_in[2];
    const float* bq  = (const float*)d_in[3];
    const float* gq  = (const float*)d_in[4];
    const float* btq = (const float*)d_in[5];
    const float* mq  = (const float*)d_in[6];
    const float* vq  = (const float*)d_in[7];
    const float* Wk  = (const float*)d_in[8];
    const float* bk  = (const float*)d_in[9];
    const float* gk  = (const float*)d_in[10];
    const float* btk = (const float*)d_in[11];
    const float* mk  = (const float*)d_in[12];
    const float* vk  = (const float*)d_in[13];
    const float* Wv  = (const float*)d_in[14];
    const float* bv  = (const float*)d_in[15];
    const float* gv  = (const float*)d_in[16];
    const float* btv = (const float*)d_in[17];
    const float* mv  = (const float*)d_in[18];
    const float* vv  = (const float*)d_in[19];
    const float* Ws  = (const float*)d_in[20];
    const float* bs  = (const float*)d_in[21];
    const float* gs  = (const float*)d_in[22];
    const float* bts = (const float*)d_in[23];
    const float* ms  = (const float*)d_in[24];
    const float* vs  = (const float*)d_in[25];
    const float* Wd  = (const float*)d_in[26];
    const float* bd  = (const float*)d_in[27];
    const float* gd  = (const float*)d_in[28];
    const float* btd = (const float*)d_in[29];
    const float* md  = (const float*)d_in[30];
    const float* vd  = (const float*)d_in[31];

    char* ws = (char*)d_ws;
    unsigned short* Pp   = (unsigned short*)ws;                 // 829440 B
    unsigned short* Dp   = Pp + PADSZ;                          // 829440 B
    unsigned short* Wt   = Dp + PADSZ;                          // 3538944 B
    unsigned short* Wqkv = Wt + 2 * WTSZ;                       // 196608 B
    float* q = (float*)(ws + 5394432);
    float* k = q + QSZ;
    float* v = k + QSZ;

    prep_kernel<<<1621, 256, 0, stream>>>(Ws, Wd, Wq, Wk, Wv,
                                          (uint4*)Pp, Wt, Wqkv);

    qkv_gemm_kernel<<<256, 256, 0, stream>>>(
        x, Wqkv,
        bq, gq, btq, mq, vq,
        bk, gk, btk, mk, vk,
        bv, gv, btv, mv, vv,
        q, k, v);

    att_kernel<<<1152, 256, 0, stream>>>(q, k, v, Pp, Dp);

    conv_fused_kernel<<<256, 256, 0, stream>>>(
        Pp, Dp, Wt,
        bs, gs, bts, ms, vs,
        bd, gd, btd, md, vd,
        x, gama, (float*)d_out);
}